// Round 1
// baseline (336.842 us; speedup 1.0000x reference)
//
#include <hip/hip_runtime.h>

// TableEmbed3D: trilinear grid_sample of a [64, 32,32,32] fp32 table at 1e6
// points, align_corners=False, padding_mode='zeros'.
//
// R5 strategy (R4 + XCD-aware channel split for L2 residency):
//  - table transposed+quantized to TWO half-arrays [S=32768][32ch] bf16
//    (2 MiB each). A monolithic [S][64] layout is exactly 4 MiB = one per-XCD
//    L2, which thrashes under the 256 MB nontemporal write stream. Split
//    halves + XCD-aware block mapping (bid%8 in {0..3} -> channels 0-31,
//    {4..7} -> channels 32-63) give each XCD a 2 MiB resident table.
//  - embed: block = 64 points x 4 lanes; each lane owns 8 channels of its
//    half. Every corner gather is one dense uint4 (16 B) load; 4 lanes cover
//    the 64 B half-row. Each point's 256 B output row is written as two
//    disjoint full-128B-line nontemporal halves (by two different blocks).
//  - zeros-padding folded into per-axis weights (no per-corner cndmask).
//  - packed fp32 FMA (f32x2 -> v_pk_fma_f32) for the accumulate.
//  - nontemporal loads for x / stores for out so the streams don't evict the
//    table from L2.

constexpr int TSZ = 32;
constexpr int S   = TSZ * TSZ * TSZ;  // 32768 spatial cells
constexpr int EMB = 64;               // channels

typedef float floatx4 __attribute__((ext_vector_type(4)));
typedef float f32x2   __attribute__((ext_vector_type(2)));

__device__ __forceinline__ unsigned short f32_to_bf16_rne(float f) {
  unsigned int u = __float_as_uint(f);
  unsigned int lsb = (u >> 16) & 1u;
  u += 0x7FFFu + lsb;  // round to nearest even
  return (unsigned short)(u >> 16);
}

// ---------------------------------------------------------------------------
// Transpose [EMB, S] fp32 -> two half-arrays [S, 32] bf16 via 64x64 LDS tiles.
// grid: S/64 blocks of 256 threads.
__global__ __launch_bounds__(256) void transpose_table_k(
    const float* __restrict__ tab, unsigned short* __restrict__ tabT) {
  __shared__ float tile[EMB][EMB + 1];
  const int s_base = blockIdx.x * 64;
  const int t  = threadIdx.x;
  const int c0 = t & 63;   // inner (coalesced) index
  const int r0 = t >> 6;   // 0..3
#pragma unroll
  for (int i = 0; i < 16; ++i) {
    const int e = r0 + 4 * i;
    tile[e][c0] = tab[(size_t)e * S + (s_base + c0)];  // coalesced read
  }
  __syncthreads();
  const int hv = c0 >> 5;   // channel half 0/1
  const int ch = c0 & 31;   // channel within half
#pragma unroll
  for (int i = 0; i < 16; ++i) {
    const int s = r0 + 4 * i;
    tabT[(size_t)hv * S * 32 + (size_t)(s_base + s) * 32 + ch] =
        f32_to_bf16_rne(tile[c0][s]);
  }
}

// ---------------------------------------------------------------------------
// Main kernel: block = 64 points x 4 lanes; half chosen by XCD group.
// tabT viewed as uint4*: half hv's row lin occupies elements
// [hv*S*4 + lin*4 .. +3]; lane o reads element lin*4 + o (16 B = 8 channels).
__global__ __launch_bounds__(256) void embed_k(
    const float* __restrict__ x, const uint4* __restrict__ tabT,
    float* __restrict__ out, int n, int nchunks) {
  const int bid = blockIdx.x;
  const int hv    = (bid >> 2) & 1;            // bid%8 in {0..3} -> 0, {4..7} -> 1
  const int chunk = (bid >> 3) * 4 + (bid & 3);  // bijective per half
  if (chunk >= nchunks) return;
  const int t  = threadIdx.x;
  const int pt = chunk * 64 + (t >> 2);
  if (pt >= n) return;
  const int o  = t & 3;  // channel octet within half (8 channels each)

  // clip to [-1,1] then align_corners=False pixel mapping:
  // pix = ((g + 1) * 32 - 1) / 2
  const float gx = fminf(fmaxf(__builtin_nontemporal_load(&x[3 * pt + 0]), -1.f), 1.f);
  const float gy = fminf(fmaxf(__builtin_nontemporal_load(&x[3 * pt + 1]), -1.f), 1.f);
  const float gz = fminf(fmaxf(__builtin_nontemporal_load(&x[3 * pt + 2]), -1.f), 1.f);
  const float px = ((gx + 1.f) * 32.f - 1.f) * 0.5f;
  const float py = ((gy + 1.f) * 32.f - 1.f) * 0.5f;
  const float pz = ((gz + 1.f) * 32.f - 1.f) * 0.5f;

  const float fxf = floorf(px), fyf = floorf(py), fzf = floorf(pz);
  const int ix0 = (int)fxf, iy0 = (int)fyf, iz0 = (int)fzf;
  const float fx = px - fxf, fy = py - fyf, fz = pz - fzf;

  // zeros padding factorized into per-axis weights: w*inb =
  // (wz*bz)*(wy*by)*(wx*bx). Clamped index is irrelevant when weight==0.
  float wxe[2], wye[2], wze[2];
  int   ixc[2], iyc[2], izc[2];
  wxe[0] = (ix0 >= 0)       ? (1.f - fx) : 0.f;
  wxe[1] = (ix0 + 1 < TSZ)  ? fx         : 0.f;
  ixc[0] = max(ix0, 0);
  ixc[1] = min(ix0 + 1, TSZ - 1);
  wye[0] = (iy0 >= 0)       ? (1.f - fy) : 0.f;
  wye[1] = (iy0 + 1 < TSZ)  ? fy         : 0.f;
  iyc[0] = max(iy0, 0);
  iyc[1] = min(iy0 + 1, TSZ - 1);
  wze[0] = (iz0 >= 0)       ? (1.f - fz) : 0.f;
  wze[1] = (iz0 + 1 < TSZ)  ? fz         : 0.f;
  izc[0] = max(iz0, 0);
  izc[1] = min(iz0 + 1, TSZ - 1);

  const uint4* tb = tabT + (size_t)hv * (S * 4);

  f32x2 a01 = {0.f, 0.f}, a23 = {0.f, 0.f}, a45 = {0.f, 0.f}, a67 = {0.f, 0.f};

#pragma unroll
  for (int dz = 0; dz < 2; ++dz) {
    const int zb = izc[dz] * (TSZ * TSZ);
#pragma unroll
    for (int dy = 0; dy < 2; ++dy) {
      const int   zyb = zb + iyc[dy] * TSZ;
      const float wzy = wze[dz] * wye[dy];
#pragma unroll
      for (int dx = 0; dx < 2; ++dx) {
        const float w   = wzy * wxe[dx];
        const int   lin = zyb + ixc[dx];
        const uint4 q   = tb[lin * 4 + o];
        const f32x2 w2  = {w, w};
        const f32x2 v01 = {__uint_as_float(q.x << 16),
                           __uint_as_float(q.x & 0xFFFF0000u)};
        const f32x2 v23 = {__uint_as_float(q.y << 16),
                           __uint_as_float(q.y & 0xFFFF0000u)};
        const f32x2 v45 = {__uint_as_float(q.z << 16),
                           __uint_as_float(q.z & 0xFFFF0000u)};
        const f32x2 v67 = {__uint_as_float(q.w << 16),
                           __uint_as_float(q.w & 0xFFFF0000u)};
        a01 = __builtin_elementwise_fma(v01, w2, a01);
        a23 = __builtin_elementwise_fma(v23, w2, a23);
        a45 = __builtin_elementwise_fma(v45, w2, a45);
        a67 = __builtin_elementwise_fma(v67, w2, a67);
      }
    }
  }

  // out: point row = 64 floats; this block owns floats [hv*32 .. hv*32+31],
  // lane o owns floats [hv*32 + o*8 .. +7] (two 16 B nt-stores, full lines
  // per point-half).
  const floatx4 s0 = {a01.x, a01.y, a23.x, a23.y};
  const floatx4 s1 = {a45.x, a45.y, a67.x, a67.y};
  float* dstp = out + (size_t)pt * EMB + hv * 32 + o * 8;
  __builtin_nontemporal_store(s0, (floatx4*)dstp);
  __builtin_nontemporal_store(s1, (floatx4*)(dstp + 4));
}

// ---------------------------------------------------------------------------
// Fallback (workspace too small): 1 thread per (point, channel), reads the
// original [E, S] fp32 layout. Slow but correct.
__global__ __launch_bounds__(256) void embed_fallback_k(
    const float* __restrict__ x, const float* __restrict__ tab,
    float* __restrict__ out, int n) {
  const int gid = blockIdx.x * 256 + threadIdx.x;
  const int pt  = gid >> 6;
  if (pt >= n) return;
  const int e = gid & 63;

  const float gx = fminf(fmaxf(x[3 * pt + 0], -1.f), 1.f);
  const float gy = fminf(fmaxf(x[3 * pt + 1], -1.f), 1.f);
  const float gz = fminf(fmaxf(x[3 * pt + 2], -1.f), 1.f);
  const float px = ((gx + 1.f) * 32.f - 1.f) * 0.5f;
  const float py = ((gy + 1.f) * 32.f - 1.f) * 0.5f;
  const float pz = ((gz + 1.f) * 32.f - 1.f) * 0.5f;

  const float fxf = floorf(px), fyf = floorf(py), fzf = floorf(pz);
  const int ix0 = (int)fxf, iy0 = (int)fyf, iz0 = (int)fzf;
  const float fx = px - fxf, fy = py - fyf, fz = pz - fzf;
  const float wx[2] = {1.f - fx, fx};
  const float wy[2] = {1.f - fy, fy};
  const float wz[2] = {1.f - fz, fz};

  float acc = 0.f;
#pragma unroll
  for (int dz = 0; dz < 2; ++dz) {
    const int  iz  = iz0 + dz;
    const bool bz  = (unsigned)iz < (unsigned)TSZ;
    const int  izc = min(max(iz, 0), TSZ - 1);
#pragma unroll
    for (int dy = 0; dy < 2; ++dy) {
      const int  iy  = iy0 + dy;
      const bool by  = (unsigned)iy < (unsigned)TSZ;
      const int  iyc = min(max(iy, 0), TSZ - 1);
#pragma unroll
      for (int dx = 0; dx < 2; ++dx) {
        const int  ix  = ix0 + dx;
        const bool bx  = (unsigned)ix < (unsigned)TSZ;
        const int  ixc = min(max(ix, 0), TSZ - 1);
        float w = wz[dz] * wy[dy] * wx[dx];
        w = (bx && by && bz) ? w : 0.f;
        const int lin = (izc * TSZ + iyc) * TSZ + ixc;
        acc = fmaf(w, tab[(size_t)e * S + lin], acc);
      }
    }
  }
  out[(size_t)pt * EMB + e] = acc;
}

// ---------------------------------------------------------------------------
extern "C" void kernel_launch(void* const* d_in, const int* in_sizes, int n_in,
                              void* d_out, int out_size, void* d_ws,
                              size_t ws_size, hipStream_t stream) {
  const float* x   = (const float*)d_in[0];
  const float* tab = (const float*)d_in[1];
  float*       out = (float*)d_out;
  const int n = in_sizes[0] / 3;

  const size_t need = (size_t)S * EMB * sizeof(unsigned short);  // 4 MiB
  if (ws_size >= need) {
    unsigned short* tabT = (unsigned short*)d_ws;
    transpose_table_k<<<S / 64, 256, 0, stream>>>(tab, tabT);
    const int C = (n + 63) / 64;             // point chunks (64 pts each)
    const int G = ((2 * C + 7) / 8) * 8;     // pad grid to a multiple of 8
    embed_k<<<G, 256, 0, stream>>>(x, (const uint4*)tabT, out, n, C);
  } else {
    const int total  = n * EMB;
    const int blocks = (total + 255) / 256;
    embed_fallback_k<<<blocks, 256, 0, stream>>>(x, tab, out, n);
  }
}

// Round 2
// 309.560 us; speedup vs baseline: 1.0881x; 1.0881x over previous
//
#include <hip/hip_runtime.h>

// TableEmbed3D: trilinear grid_sample of a [64, 32,32,32] fp32 table at 1e6
// points, align_corners=False, padding_mode='zeros'.
//
// R6 strategy (R4 gather path + full-line nontemporal stores):
//  - table transposed+quantized to [S=32768][64] bf16 in d_ws (4 MiB).
//    (R5's XCD channel-split was a measured regression: L2 footprint is not
//    the bottleneck; reverted.)
//  - embed: 8 lanes per point, each lane owns 8 channels. Every corner gather
//    is one dense uint4 (16 B) load; 8 lanes cover the full 128 B row.
//  - NEW: store epilogue redistributes accumulators across the 8-lane group
//    (16 __shfl + selects) so each of the two NT store instructions writes a
//    CONTIGUOUS 128 B line per point (bytes [0,128) then [128,256) of the
//    row). Previous layout wrote strided 16-of-32 B per instruction, which
//    under nontemporal (no-allocate) streaming is half-filled lines -> ~2x
//    write amplification on the 256 MB output stream.
//  - zeros padding folded into per-axis weights (no per-corner cndmask).
//  - packed fp32 FMA (f32x2 -> v_pk_fma_f32) for the accumulate.
//  - nontemporal loads for x (streaming) so the read stream doesn't pollute.

constexpr int TSZ = 32;
constexpr int S   = TSZ * TSZ * TSZ;  // 32768 spatial cells
constexpr int EMB = 64;               // channels

typedef float floatx4 __attribute__((ext_vector_type(4)));
typedef float f32x2   __attribute__((ext_vector_type(2)));

__device__ __forceinline__ unsigned short f32_to_bf16_rne(float f) {
  unsigned int u = __float_as_uint(f);
  unsigned int lsb = (u >> 16) & 1u;
  u += 0x7FFFu + lsb;  // round to nearest even
  return (unsigned short)(u >> 16);
}

// ---------------------------------------------------------------------------
// Transpose [EMB, S] fp32 -> [S, EMB] bf16 via 64x64 LDS tiles (+1 pad).
// grid: S/64 blocks of 256 threads.
__global__ __launch_bounds__(256) void transpose_table_k(
    const float* __restrict__ tab, unsigned short* __restrict__ tabT) {
  __shared__ float tile[EMB][EMB + 1];
  const int s_base = blockIdx.x * 64;
  const int t  = threadIdx.x;
  const int c0 = t & 63;   // inner (coalesced) index
  const int r0 = t >> 6;   // 0..3
#pragma unroll
  for (int i = 0; i < 16; ++i) {
    const int e = r0 + 4 * i;
    tile[e][c0] = tab[(size_t)e * S + (s_base + c0)];  // coalesced read
  }
  __syncthreads();
#pragma unroll
  for (int i = 0; i < 16; ++i) {
    const int s = r0 + 4 * i;
    tabT[(size_t)(s_base + s) * EMB + c0] = f32_to_bf16_rne(tile[c0][s]);
  }
}

// ---------------------------------------------------------------------------
// Main kernel: 8 threads per point, each thread computes 8 channels.
// tabT viewed as uint4* : row lin occupies elements [lin*8 .. lin*8+7];
// lane c8 reads element lin*8 + c8 (16 B = 8 bf16 channels).
__global__ __launch_bounds__(256) void embed_k(
    const float* __restrict__ x, const uint4* __restrict__ tabT,
    float* __restrict__ out, int n) {
  const int gid = blockIdx.x * 256 + threadIdx.x;
  const int pt  = gid >> 3;
  if (pt >= n) return;
  const int c8 = gid & 7;  // channel octet (8 channels each)

  // clip to [-1,1] then align_corners=False pixel mapping:
  // pix = ((g + 1) * 32 - 1) / 2
  const float gx = fminf(fmaxf(__builtin_nontemporal_load(&x[3 * pt + 0]), -1.f), 1.f);
  const float gy = fminf(fmaxf(__builtin_nontemporal_load(&x[3 * pt + 1]), -1.f), 1.f);
  const float gz = fminf(fmaxf(__builtin_nontemporal_load(&x[3 * pt + 2]), -1.f), 1.f);
  const float px = ((gx + 1.f) * 32.f - 1.f) * 0.5f;
  const float py = ((gy + 1.f) * 32.f - 1.f) * 0.5f;
  const float pz = ((gz + 1.f) * 32.f - 1.f) * 0.5f;

  const float fxf = floorf(px), fyf = floorf(py), fzf = floorf(pz);
  const int ix0 = (int)fxf, iy0 = (int)fyf, iz0 = (int)fzf;
  const float fx = px - fxf, fy = py - fyf, fz = pz - fzf;

  // zeros padding factorized into per-axis weights: w*inb =
  // (wz*bz)*(wy*by)*(wx*bx). Clamped index is irrelevant when weight==0.
  float wxe[2], wye[2], wze[2];
  int   ixc[2], iyc[2], izc[2];
  wxe[0] = (ix0 >= 0)       ? (1.f - fx) : 0.f;
  wxe[1] = (ix0 + 1 < TSZ)  ? fx         : 0.f;
  ixc[0] = max(ix0, 0);
  ixc[1] = min(ix0 + 1, TSZ - 1);
  wye[0] = (iy0 >= 0)       ? (1.f - fy) : 0.f;
  wye[1] = (iy0 + 1 < TSZ)  ? fy         : 0.f;
  iyc[0] = max(iy0, 0);
  iyc[1] = min(iy0 + 1, TSZ - 1);
  wze[0] = (iz0 >= 0)       ? (1.f - fz) : 0.f;
  wze[1] = (iz0 + 1 < TSZ)  ? fz         : 0.f;
  izc[0] = max(iz0, 0);
  izc[1] = min(iz0 + 1, TSZ - 1);

  f32x2 a01 = {0.f, 0.f}, a23 = {0.f, 0.f}, a45 = {0.f, 0.f}, a67 = {0.f, 0.f};

#pragma unroll
  for (int dz = 0; dz < 2; ++dz) {
    const int zb = izc[dz] * (TSZ * TSZ);
#pragma unroll
    for (int dy = 0; dy < 2; ++dy) {
      const int   zyb = zb + iyc[dy] * TSZ;
      const float wzy = wze[dz] * wye[dy];
#pragma unroll
      for (int dx = 0; dx < 2; ++dx) {
        const float w   = wzy * wxe[dx];
        const int   lin = zyb + ixc[dx];
        const uint4 q   = tabT[lin * 8 + c8];
        const f32x2 w2  = {w, w};
        const f32x2 v01 = {__uint_as_float(q.x << 16),
                           __uint_as_float(q.x & 0xFFFF0000u)};
        const f32x2 v23 = {__uint_as_float(q.y << 16),
                           __uint_as_float(q.y & 0xFFFF0000u)};
        const f32x2 v45 = {__uint_as_float(q.z << 16),
                           __uint_as_float(q.z & 0xFFFF0000u)};
        const f32x2 v67 = {__uint_as_float(q.w << 16),
                           __uint_as_float(q.w & 0xFFFF0000u)};
        a01 = __builtin_elementwise_fma(v01, w2, a01);
        a23 = __builtin_elementwise_fma(v23, w2, a23);
        a45 = __builtin_elementwise_fma(v45, w2, a45);
        a67 = __builtin_elementwise_fma(v67, w2, a67);
      }
    }
  }

  // -------------------------------------------------------------------------
  // Epilogue: redistribute so each NT store instruction writes a CONTIGUOUS
  // 128 B per point. Store 1 covers row bytes [0,128): lane c8 writes floats
  // [c8*4, c8*4+4) = channels c8*4+j, owned by lane grp+(c8>>1) at element
  // (c8&1)*4+j. Store 2 covers bytes [128,256) analogously from lanes
  // grp+4+(c8>>1).
  const float accv[8] = {a01.x, a01.y, a23.x, a23.y, a45.x, a45.y, a67.x, a67.y};
  const int lane = threadIdx.x & 63;
  const int grp  = lane & ~7;            // 8-lane point group within the wave
  const int src1 = grp + (c8 >> 1);
  const int src2 = grp + 4 + (c8 >> 1);
  const bool hi  = (c8 & 1) != 0;
  float o0[4], o1[4];
#pragma unroll
  for (int j = 0; j < 4; ++j) {
    const float aj = __shfl(accv[j],     src1, 64);
    const float bj = __shfl(accv[4 + j], src1, 64);
    o0[j] = hi ? bj : aj;
    const float cj = __shfl(accv[j],     src2, 64);
    const float dj = __shfl(accv[4 + j], src2, 64);
    o1[j] = hi ? dj : cj;
  }
  const floatx4 s0 = {o0[0], o0[1], o0[2], o0[3]};
  const floatx4 s1 = {o1[0], o1[1], o1[2], o1[3]};
  float* rowp = out + (size_t)pt * EMB;  // 256 B output row
  __builtin_nontemporal_store(s0, (floatx4*)(rowp + c8 * 4));       // [0,128)
  __builtin_nontemporal_store(s1, (floatx4*)(rowp + 32 + c8 * 4));  // [128,256)
}

// ---------------------------------------------------------------------------
// Fallback (workspace too small): 1 thread per (point, channel), reads the
// original [E, S] fp32 layout. Slow but correct.
__global__ __launch_bounds__(256) void embed_fallback_k(
    const float* __restrict__ x, const float* __restrict__ tab,
    float* __restrict__ out, int n) {
  const int gid = blockIdx.x * 256 + threadIdx.x;
  const int pt  = gid >> 6;
  if (pt >= n) return;
  const int e = gid & 63;

  const float gx = fminf(fmaxf(x[3 * pt + 0], -1.f), 1.f);
  const float gy = fminf(fmaxf(x[3 * pt + 1], -1.f), 1.f);
  const float gz = fminf(fmaxf(x[3 * pt + 2], -1.f), 1.f);
  const float px = ((gx + 1.f) * 32.f - 1.f) * 0.5f;
  const float py = ((gy + 1.f) * 32.f - 1.f) * 0.5f;
  const float pz = ((gz + 1.f) * 32.f - 1.f) * 0.5f;

  const float fxf = floorf(px), fyf = floorf(py), fzf = floorf(pz);
  const int ix0 = (int)fxf, iy0 = (int)fyf, iz0 = (int)fzf;
  const float fx = px - fxf, fy = py - fyf, fz = pz - fzf;
  const float wx[2] = {1.f - fx, fx};
  const float wy[2] = {1.f - fy, fy};
  const float wz[2] = {1.f - fz, fz};

  float acc = 0.f;
#pragma unroll
  for (int dz = 0; dz < 2; ++dz) {
    const int  iz  = iz0 + dz;
    const bool bz  = (unsigned)iz < (unsigned)TSZ;
    const int  izc = min(max(iz, 0), TSZ - 1);
#pragma unroll
    for (int dy = 0; dy < 2; ++dy) {
      const int  iy  = iy0 + dy;
      const bool by  = (unsigned)iy < (unsigned)TSZ;
      const int  iyc = min(max(iy, 0), TSZ - 1);
#pragma unroll
      for (int dx = 0; dx < 2; ++dx) {
        const int  ix  = ix0 + dx;
        const bool bx  = (unsigned)ix < (unsigned)TSZ;
        const int  ixc = min(max(ix, 0), TSZ - 1);
        float w = wz[dz] * wy[dy] * wx[dx];
        w = (bx && by && bz) ? w : 0.f;
        const int lin = (izc * TSZ + iyc) * TSZ + ixc;
        acc = fmaf(w, tab[(size_t)e * S + lin], acc);
      }
    }
  }
  out[(size_t)pt * EMB + e] = acc;
}

// ---------------------------------------------------------------------------
extern "C" void kernel_launch(void* const* d_in, const int* in_sizes, int n_in,
                              void* d_out, int out_size, void* d_ws,
                              size_t ws_size, hipStream_t stream) {
  const float* x   = (const float*)d_in[0];
  const float* tab = (const float*)d_in[1];
  float*       out = (float*)d_out;
  const int n = in_sizes[0] / 3;

  const size_t need = (size_t)S * EMB * sizeof(unsigned short);  // 4 MiB
  if (ws_size >= need) {
    unsigned short* tabT = (unsigned short*)d_ws;
    transpose_table_k<<<S / 64, 256, 0, stream>>>(tab, tabT);
    const int total  = n * 8;  // 8 threads per point
    const int blocks = (total + 255) / 256;
    embed_k<<<blocks, 256, 0, stream>>>(x, (const uint4*)tabT, out, n);
  } else {
    const int total  = n * EMB;
    const int blocks = (total + 255) / 256;
    embed_fallback_k<<<blocks, 256, 0, stream>>>(x, tab, out, n);
  }
}